// Round 5
// baseline (124.950 us; speedup 1.0000x reference)
//
#include <hip/hip_runtime.h>

// SOM BMU: argmin_m (w_sq[m] - 2*dot(x,w[m])) -> (idx/128, idx%128).
// f16 hi/lo split (3 MFMAs per fp32 product, fp32-accurate), 256x256 tile,
// 8 waves, 4-phase-per-K-step pipeline (m201-style: interleaved ds_read /
// global_load_lds / MFMA clusters, counted waits, setprio), tile-major
// intermediate layout -> linear conflict-free LDS, atomicMin(u64) argmin.

#define B_ROWS 4096
#define M_COLS 16384
#define KF 256
#define BM 256
#define BN 256
#define NK 8              // K-steps of BK=32

typedef _Float16 f16x8 __attribute__((ext_vector_type(8)));
typedef float f32x4 __attribute__((ext_vector_type(4)));
typedef unsigned long long u64;

#define GLOAD16(gsrc, ldst) \
  __builtin_amdgcn_global_load_lds((const __attribute__((address_space(1))) void*)(gsrc), \
                                   (__attribute__((address_space(3))) void*)(ldst), 16, 0, 0)

#define BAR()        asm volatile("s_barrier" ::: "memory")
#define WAIT_LGKM0() do { asm volatile("s_waitcnt lgkmcnt(0)" ::: "memory"); \
                          __builtin_amdgcn_sched_barrier(0); } while (0)
#define WAIT_VM0()   asm volatile("s_waitcnt vmcnt(0)" ::: "memory")

// tile-major: tiles of 256 rows; per (tile,ks): [kch=4][r=256][8] halves = 16 KB
__device__ __forceinline__ size_t tm_idx(int tile, int ks, int kch, int r) {
    return ((((size_t)(tile * 8 + ks)) * 4 + kch) * 256 + r) * 8;
}

// ---------------- kernel 1: split W -> tile-major f16 hi/lo + w_sq ----------------
__global__ __launch_bounds__(256) void som_split_w(const float* __restrict__ wt,
                                                   _Float16* __restrict__ whi,
                                                   _Float16* __restrict__ wlo,
                                                   float* __restrict__ wsq) {
    const int gid = blockIdx.x * 256 + threadIdx.x;
    const int row = gid >> 5;          // 32 threads per row
    const int kg = gid & 31;           // 8-element k-group
    const float4 v0 = *reinterpret_cast<const float4*>(wt + (size_t)row * KF + kg * 8);
    const float4 v1 = *reinterpret_cast<const float4*>(wt + (size_t)row * KF + kg * 8 + 4);
    const float vv[8] = {v0.x, v0.y, v0.z, v0.w, v1.x, v1.y, v1.z, v1.w};
    f16x8 h, l;
    float s = 0.0f;
#pragma unroll
    for (int j = 0; j < 8; ++j) {
        h[j] = (_Float16)vv[j];
        l[j] = (_Float16)(vv[j] - (float)h[j]);
        s += vv[j] * vv[j];
    }
    const size_t e = tm_idx(row >> 8, kg >> 2, kg & 3, row & 255);
    *reinterpret_cast<f16x8*>(whi + e) = h;
    *reinterpret_cast<f16x8*>(wlo + e) = l;
#pragma unroll
    for (int off = 16; off > 0; off >>= 1) s += __shfl_down(s, off, 64);
    if (kg == 0) wsq[row] = s;   // lanes 0 and 32 each own a row
}

// ---------------- kernel 2: split X -> tile-major f16 hi/lo; init part ----------------
__global__ __launch_bounds__(256) void som_split_x(const float* __restrict__ xb,
                                                   _Float16* __restrict__ xhi,
                                                   _Float16* __restrict__ xlo,
                                                   u64* __restrict__ part) {
    const int gid = blockIdx.x * 256 + threadIdx.x;
    if (gid < B_ROWS) part[gid] = ~0ull;
    const int row = gid >> 5;
    const int kg = gid & 31;
    const float4 v0 = *reinterpret_cast<const float4*>(xb + (size_t)row * KF + kg * 8);
    const float4 v1 = *reinterpret_cast<const float4*>(xb + (size_t)row * KF + kg * 8 + 4);
    const float vv[8] = {v0.x, v0.y, v0.z, v0.w, v1.x, v1.y, v1.z, v1.w};
    f16x8 h, l;
#pragma unroll
    for (int j = 0; j < 8; ++j) {
        h[j] = (_Float16)vv[j];
        l[j] = (_Float16)(vv[j] - (float)h[j]);
    }
    const size_t e = tm_idx(row >> 8, kg >> 2, kg & 3, row & 255);
    *reinterpret_cast<f16x8*>(xhi + e) = h;
    *reinterpret_cast<f16x8*>(xlo + e) = l;
}

// ---------------- kernel 3: 256x256 MFMA GEMM + fused argmin ----------------
__global__ __launch_bounds__(512, 2) void som_main(const _Float16* __restrict__ xhi,
                                                   const _Float16* __restrict__ xlo,
                                                   const _Float16* __restrict__ whi,
                                                   const _Float16* __restrict__ wlo,
                                                   const float* __restrict__ wsq,
                                                   u64* __restrict__ part) {
    __shared__ _Float16 lds[2][4][8192];   // [buf][Ah,Al,Bh,Bl][kch=4][r=256][8], 128 KB

    const int tid = threadIdx.x;
    const int lane = tid & 63;
    const int frow = lane & 15;
    const int kch = lane >> 4;
    const int wid = tid >> 6;
    const int wr = wid >> 2;      // 0..1: wave row, owns 128 rows
    const int wc = wid & 3;       // 0..3: wave col, owns 64 cols

    // bijective XCD swizzle (1024 blocks, 1024%8==0); same-XCD blocks share col-panels
    const int bid = blockIdx.x;
    const int swz = (bid & 7) * 128 + (bid >> 3);
    const int by = swz >> 4;      // col tile 0..63
    const int bx = swz & 15;      // row tile 0..15
    const int rowbase = bx * BM;
    const int colbase = by * BN;

    const int ebase = (tid & 448) * 8;   // wave-uniform LDS base (halves)
    const int tid8 = tid * 8;

    f32x4 acc[8][4];
#pragma unroll
    for (int m = 0; m < 8; ++m)
#pragma unroll
        for (int n = 0; n < 4; ++n) acc[m][n] = (f32x4){0.f, 0.f, 0.f, 0.f};
    f16x8 bh[4], bl[4];

    // prologue: stage step 0 fully, drain once
    {
        const size_t ab = (size_t)(bx * 8) * 8192;
        const size_t bb = (size_t)(by * 8) * 8192;
        GLOAD16(xhi + ab + tid8,        &lds[0][0][ebase]);
        GLOAD16(xhi + ab + 4096 + tid8, &lds[0][0][4096 + ebase]);
        GLOAD16(xlo + ab + tid8,        &lds[0][1][ebase]);
        GLOAD16(xlo + ab + 4096 + tid8, &lds[0][1][4096 + ebase]);
        GLOAD16(whi + bb + tid8,        &lds[0][2][ebase]);
        GLOAD16(whi + bb + 4096 + tid8, &lds[0][2][4096 + ebase]);
        GLOAD16(wlo + bb + tid8,        &lds[0][3][ebase]);
        GLOAD16(wlo + bb + 4096 + tid8, &lds[0][3][4096 + ebase]);
    }
    __syncthreads();

#define PHASE(p_, ARR_, GSRC_, GB_)                                           \
    {                                                                         \
        const int offa0 = kch * 2048 + (wr * 128 + (2 * (p_)) * 16 + frow) * 8; \
        const int offa1 = offa0 + 128;                                        \
        const f16x8 ah0 = *reinterpret_cast<const f16x8*>(&lds[buf][0][offa0]); \
        const f16x8 ah1 = *reinterpret_cast<const f16x8*>(&lds[buf][0][offa1]); \
        const f16x8 al0 = *reinterpret_cast<const f16x8*>(&lds[buf][1][offa0]); \
        const f16x8 al1 = *reinterpret_cast<const f16x8*>(&lds[buf][1][offa1]); \
        if ((p_) == 0) {                                                      \
            _Pragma("unroll")                                                 \
            for (int n = 0; n < 4; ++n) {                                     \
                const int offb = kch * 2048 + (wc * 64 + n * 16 + frow) * 8;  \
                bh[n] = *reinterpret_cast<const f16x8*>(&lds[buf][2][offb]);  \
                bl[n] = *reinterpret_cast<const f16x8*>(&lds[buf][3][offb]);  \
            }                                                                 \
        }                                                                     \
        if (t < NK - 1) {                                                     \
            GLOAD16((GSRC_) + (GB_) + tid8,        &lds[buf ^ 1][ARR_][ebase]); \
            GLOAD16((GSRC_) + (GB_) + 4096 + tid8, &lds[buf ^ 1][ARR_][4096 + ebase]); \
        }                                                                     \
        BAR();                                                                \
        WAIT_LGKM0();                                                         \
        __builtin_amdgcn_s_setprio(1);                                        \
        _Pragma("unroll")                                                     \
        for (int n = 0; n < 4; ++n) {                                         \
            acc[2*(p_)][n]   = __builtin_amdgcn_mfma_f32_16x16x32_f16(ah0, bh[n], acc[2*(p_)][n], 0, 0, 0); \
            acc[2*(p_)+1][n] = __builtin_amdgcn_mfma_f32_16x16x32_f16(ah1, bh[n], acc[2*(p_)+1][n], 0, 0, 0); \
        }                                                                     \
        _Pragma("unroll")                                                     \
        for (int n = 0; n < 4; ++n) {                                         \
            acc[2*(p_)][n]   = __builtin_amdgcn_mfma_f32_16x16x32_f16(ah0, bl[n], acc[2*(p_)][n], 0, 0, 0); \
            acc[2*(p_)+1][n] = __builtin_amdgcn_mfma_f32_16x16x32_f16(ah1, bl[n], acc[2*(p_)+1][n], 0, 0, 0); \
        }                                                                     \
        _Pragma("unroll")                                                     \
        for (int n = 0; n < 4; ++n) {                                         \
            acc[2*(p_)][n]   = __builtin_amdgcn_mfma_f32_16x16x32_f16(al0, bh[n], acc[2*(p_)][n], 0, 0, 0); \
            acc[2*(p_)+1][n] = __builtin_amdgcn_mfma_f32_16x16x32_f16(al1, bh[n], acc[2*(p_)+1][n], 0, 0, 0); \
        }                                                                     \
        __builtin_amdgcn_s_setprio(0);                                        \
        if ((p_) == 3 && t < NK - 1) WAIT_VM0();                              \
        BAR();                                                                \
    }

    for (int t = 0; t < NK; ++t) {
        const int buf = t & 1;
        const size_t abn = (size_t)(bx * 8 + t + 1) * 8192;   // deref'd only if t<NK-1
        const size_t bbn = (size_t)(by * 8 + t + 1) * 8192;
        PHASE(0, 0, xhi, abn)
        PHASE(1, 1, xlo, abn)
        PHASE(2, 2, whi, bbn)
        PHASE(3, 3, wlo, bbn)
    }
#undef PHASE

    // ---- epilogue: score, per-row argmin, cross-wave reduce, atomicMin ----
    __syncthreads();
    u64* red = reinterpret_cast<u64*>(&lds[0][0][0]);   // [256 rows][4 wc] u64 = 8 KB
    float wq[4];
#pragma unroll
    for (int n = 0; n < 4; ++n) wq[n] = wsq[colbase + wc * 64 + n * 16 + frow];

#pragma unroll
    for (int m = 0; m < 8; ++m)
#pragma unroll
        for (int r = 0; r < 4; ++r) {
            u64 b = ~0ull;
#pragma unroll
            for (int n = 0; n < 4; ++n) {
                const int colg = colbase + wc * 64 + n * 16 + frow;
                const float sc = wq[n] - 2.0f * acc[m][n][r];
                const unsigned int fb = __float_as_uint(sc);
                const unsigned int key = (fb & 0x80000000u) ? ~fb : (fb | 0x80000000u);
                const u64 p = ((u64)key << 32) | (unsigned int)colg;
                if (p < b) b = p;
            }
            // reduce over the 16 frow lanes (same kch group)
#pragma unroll
            for (int mk = 1; mk <= 8; mk <<= 1) {
                const u64 o = __shfl_xor(b, mk, 64);
                if (o < b) b = o;
            }
            if (frow == 0) {
                const int rl = wr * 128 + m * 16 + kch * 4 + r;
                red[rl * 4 + wc] = b;
            }
        }
    __syncthreads();
    if (tid < BM) {
        u64 a = red[tid * 4];
#pragma unroll
        for (int j = 1; j < 4; ++j) {
            const u64 o = red[tid * 4 + j];
            if (o < a) a = o;
        }
        atomicMin(part + rowbase + tid, a);
    }
}

// ---------------- kernel 4: decode ----------------
__global__ __launch_bounds__(256) void som_decode(const u64* __restrict__ part,
                                                  int* __restrict__ out) {
    const int row = blockIdx.x * 256 + threadIdx.x;
    if (row >= B_ROWS) return;
    const int idx = (int)(part[row] & 0xFFFFFFFFu);
    out[2 * row] = idx >> 7;      // idx / 128
    out[2 * row + 1] = idx & 127; // idx % 128
}

extern "C" void kernel_launch(void* const* d_in, const int* in_sizes, int n_in,
                              void* d_out, int out_size, void* d_ws, size_t ws_size,
                              hipStream_t stream) {
    const float* xb = (const float*)d_in[0];   // [4096, 256] fp32
    const float* wt = (const float*)d_in[1];   // [16384, 256] fp32
    int* out = (int*)d_out;                    // [4096, 2] int32

    char* ws = (char*)d_ws;
    _Float16* xhi = (_Float16*)(ws);                                   // 2 MB
    _Float16* xlo = (_Float16*)(ws + (size_t)2 * 1024 * 1024);         // 2 MB
    _Float16* whi = (_Float16*)(ws + (size_t)4 * 1024 * 1024);         // 8 MB
    _Float16* wlo = (_Float16*)(ws + (size_t)12 * 1024 * 1024);        // 8 MB
    float*    wsq = (float*)(ws + (size_t)20 * 1024 * 1024);           // 64 KB
    u64*     part = (u64*)(ws + (size_t)20 * 1024 * 1024 + 65536);     // 32 KB

    som_split_w<<<(M_COLS * 32) / 256, 256, 0, stream>>>(wt, whi, wlo, wsq);
    som_split_x<<<(B_ROWS * 32) / 256, 256, 0, stream>>>(xb, xhi, xlo, part);
    som_main<<<(B_ROWS / BM) * (M_COLS / BN), 512, 0, stream>>>(xhi, xlo, whi, wlo, wsq, part);
    som_decode<<<B_ROWS / 256, 256, 0, stream>>>(part, out);
}

// Round 6
// 124.553 us; speedup vs baseline: 1.0032x; 1.0032x over previous
//
#include <hip/hip_runtime.h>

// SOM BMU: argmin_m (w_sq[m] - 2*dot(x,w[m])) -> (idx/128, idx%128).
// f16 hi/lo split (3 MFMAs per fp32 product, fp32-accurate), 256x256 tile,
// 8 waves. K-loop split into 3 phases per BK=32 step, one MFMA pass each
// (hh/hl/lh); each phase stages its own arrays for step t+1 and waits with
// counted vmcnt(8) (never on younger loads). Tile-major intermediate layout
// -> linear conflict-free LDS. atomicMin(u64) argmin.

#define B_ROWS 4096
#define M_COLS 16384
#define KF 256
#define BM 256
#define BN 256
#define NK 8              // K-steps of BK=32

typedef _Float16 f16x8 __attribute__((ext_vector_type(8)));
typedef float f32x4 __attribute__((ext_vector_type(4)));
typedef unsigned long long u64;

#define GLOAD16(gsrc, ldst) \
  __builtin_amdgcn_global_load_lds((const __attribute__((address_space(1))) void*)(gsrc), \
                                   (__attribute__((address_space(3))) void*)(ldst), 16, 0, 0)

#define BAR()        asm volatile("s_barrier" ::: "memory")
#define WAIT_LGKM0() do { asm volatile("s_waitcnt lgkmcnt(0)" ::: "memory"); \
                          __builtin_amdgcn_sched_barrier(0); } while (0)
#define WAIT_VM(n)   do { asm volatile("s_waitcnt vmcnt(" #n ")" ::: "memory"); \
                          __builtin_amdgcn_sched_barrier(0); } while (0)

// tile-major: tiles of 256 rows; per (tile,ks): [kch=4][r=256][8] halves = 16 KB
__device__ __forceinline__ size_t tm_idx(int tile, int ks, int kch, int r) {
    return ((((size_t)(tile * 8 + ks)) * 4 + kch) * 256 + r) * 8;
}

// ---------------- kernel 1: split W -> tile-major f16 hi/lo + w_sq ----------------
__global__ __launch_bounds__(256) void som_split_w(const float* __restrict__ wt,
                                                   _Float16* __restrict__ whi,
                                                   _Float16* __restrict__ wlo,
                                                   float* __restrict__ wsq) {
    const int gid = blockIdx.x * 256 + threadIdx.x;
    const int row = gid >> 5;          // 32 threads per row
    const int kg = gid & 31;           // 8-element k-group
    const float4 v0 = *reinterpret_cast<const float4*>(wt + (size_t)row * KF + kg * 8);
    const float4 v1 = *reinterpret_cast<const float4*>(wt + (size_t)row * KF + kg * 8 + 4);
    const float vv[8] = {v0.x, v0.y, v0.z, v0.w, v1.x, v1.y, v1.z, v1.w};
    f16x8 h, l;
    float s = 0.0f;
#pragma unroll
    for (int j = 0; j < 8; ++j) {
        h[j] = (_Float16)vv[j];
        l[j] = (_Float16)(vv[j] - (float)h[j]);
        s += vv[j] * vv[j];
    }
    const size_t e = tm_idx(row >> 8, kg >> 2, kg & 3, row & 255);
    *reinterpret_cast<f16x8*>(whi + e) = h;
    *reinterpret_cast<f16x8*>(wlo + e) = l;
#pragma unroll
    for (int off = 16; off > 0; off >>= 1) s += __shfl_down(s, off, 64);
    if (kg == 0) wsq[row] = s;   // lanes 0 and 32 each own a row
}

// ---------------- kernel 2: split X -> tile-major f16 hi/lo; init part ----------------
__global__ __launch_bounds__(256) void som_split_x(const float* __restrict__ xb,
                                                   _Float16* __restrict__ xhi,
                                                   _Float16* __restrict__ xlo,
                                                   u64* __restrict__ part) {
    const int gid = blockIdx.x * 256 + threadIdx.x;
    if (gid < B_ROWS) part[gid] = ~0ull;
    const int row = gid >> 5;
    const int kg = gid & 31;
    const float4 v0 = *reinterpret_cast<const float4*>(xb + (size_t)row * KF + kg * 8);
    const float4 v1 = *reinterpret_cast<const float4*>(xb + (size_t)row * KF + kg * 8 + 4);
    const float vv[8] = {v0.x, v0.y, v0.z, v0.w, v1.x, v1.y, v1.z, v1.w};
    f16x8 h, l;
#pragma unroll
    for (int j = 0; j < 8; ++j) {
        h[j] = (_Float16)vv[j];
        l[j] = (_Float16)(vv[j] - (float)h[j]);
    }
    const size_t e = tm_idx(row >> 8, kg >> 2, kg & 3, row & 255);
    *reinterpret_cast<f16x8*>(xhi + e) = h;
    *reinterpret_cast<f16x8*>(xlo + e) = l;
}

// ---------------- kernel 3: 256x256 MFMA GEMM + fused argmin ----------------
__global__ __launch_bounds__(512, 2) void som_main(const _Float16* __restrict__ xhi,
                                                   const _Float16* __restrict__ xlo,
                                                   const _Float16* __restrict__ whi,
                                                   const _Float16* __restrict__ wlo,
                                                   const float* __restrict__ wsq,
                                                   u64* __restrict__ part) {
    __shared__ _Float16 lds[2][4][8192];   // [buf][Ah,Al,Bh,Bl][kch=4][r=256][8], 128 KB

    const int tid = threadIdx.x;
    const int lane = tid & 63;
    const int frow = lane & 15;
    const int kch = lane >> 4;
    const int wid = tid >> 6;
    const int wr = wid >> 2;      // 0..1: wave row, owns 128 rows
    const int wc = wid & 3;       // 0..3: wave col, owns 64 cols

    // bijective XCD swizzle (1024 blocks, 1024%8==0); same-XCD blocks share col-panels
    const int bid = blockIdx.x;
    const int swz = (bid & 7) * 128 + (bid >> 3);
    const int by = swz >> 4;      // col tile 0..63
    const int bx = swz & 15;      // row tile 0..15
    const int rowbase = bx * BM;
    const int colbase = by * BN;

    const int ebase = (tid & 448) * 8;   // wave-uniform LDS base (halves)
    const int tid8 = tid * 8;

    f32x4 acc[8][4];
#pragma unroll
    for (int m = 0; m < 8; ++m)
#pragma unroll
        for (int n = 0; n < 4; ++n) acc[m][n] = (f32x4){0.f, 0.f, 0.f, 0.f};

    // prologue: stage step 0 in steady-state issue order: Ah,Ah,Bh,Bh,Bl,Bl,Al,Al
    {
        const size_t ab = (size_t)(bx * 8) * 8192;
        const size_t bb = (size_t)(by * 8) * 8192;
        GLOAD16(xhi + ab + tid8,        &lds[0][0][ebase]);
        GLOAD16(xhi + ab + 4096 + tid8, &lds[0][0][4096 + ebase]);
        GLOAD16(whi + bb + tid8,        &lds[0][2][ebase]);
        GLOAD16(whi + bb + 4096 + tid8, &lds[0][2][4096 + ebase]);
        GLOAD16(wlo + bb + tid8,        &lds[0][3][ebase]);
        GLOAD16(wlo + bb + 4096 + tid8, &lds[0][3][4096 + ebase]);
        GLOAD16(xlo + ab + tid8,        &lds[0][1][ebase]);
        GLOAD16(xlo + ab + 4096 + tid8, &lds[0][1][4096 + ebase]);
    }

#define LDS_A(dst, arr) \
    _Pragma("unroll") \
    for (int m = 0; m < 8; ++m) \
        dst[m] = *reinterpret_cast<const f16x8*>(&lds[buf][arr][kch * 2048 + (wr * 128 + m * 16 + frow) * 8]);
#define LDS_B(dst, arr) \
    _Pragma("unroll") \
    for (int n = 0; n < 4; ++n) \
        dst[n] = *reinterpret_cast<const f16x8*>(&lds[buf][arr][kch * 2048 + (wc * 64 + n * 16 + frow) * 8]);
#define PASS(AF, BF) \
    _Pragma("unroll") \
    for (int m = 0; m < 8; ++m) \
        _Pragma("unroll") \
        for (int n = 0; n < 4; ++n) \
            acc[m][n] = __builtin_amdgcn_mfma_f32_16x16x32_f16(AF[m], BF[n], acc[m][n], 0, 0, 0);

    for (int t = 0; t < NK; ++t) {
        const int buf = t & 1;
        const int nbuf = buf ^ 1;
        const size_t abn = (size_t)(bx * 8 + t + 1) * 8192;   // deref'd only if t<NK-1
        const size_t bbn = (size_t)(by * 8 + t + 1) * 8192;

        // ---- phase A: stage next {Ah,Bh}; publish {Ah,Bh}(t); pass hh ----
        if (t < NK - 1) {
            GLOAD16(xhi + abn + tid8,        &lds[nbuf][0][ebase]);
            GLOAD16(xhi + abn + 4096 + tid8, &lds[nbuf][0][4096 + ebase]);
            GLOAD16(whi + bbn + tid8,        &lds[nbuf][2][ebase]);
            GLOAD16(whi + bbn + 4096 + tid8, &lds[nbuf][2][4096 + ebase]);
            WAIT_VM(8);
        } else {
            WAIT_VM(4);
        }
        BAR();
        f16x8 ah[8], bh[4];
        LDS_A(ah, 0)
        LDS_B(bh, 2)
        WAIT_LGKM0();
        __builtin_amdgcn_s_setprio(1);
        PASS(ah, bh)
        __builtin_amdgcn_s_setprio(0);

        // ---- phase B: stage next {Bl}; publish {Bl}(t); pass hl ----
        if (t < NK - 1) {
            GLOAD16(wlo + bbn + tid8,        &lds[nbuf][3][ebase]);
            GLOAD16(wlo + bbn + 4096 + tid8, &lds[nbuf][3][4096 + ebase]);
            WAIT_VM(8);
        } else {
            WAIT_VM(2);
        }
        BAR();
        f16x8 bl[4];
        LDS_B(bl, 3)
        WAIT_LGKM0();
        __builtin_amdgcn_s_setprio(1);
        PASS(ah, bl)
        __builtin_amdgcn_s_setprio(0);

        // ---- phase C: stage next {Al}; publish {Al}(t); pass lh ----
        if (t < NK - 1) {
            GLOAD16(xlo + abn + tid8,        &lds[nbuf][1][ebase]);
            GLOAD16(xlo + abn + 4096 + tid8, &lds[nbuf][1][4096 + ebase]);
            WAIT_VM(8);
        } else {
            WAIT_VM(0);
        }
        BAR();
        f16x8 al[8];
        LDS_A(al, 1)
        WAIT_LGKM0();
        __builtin_amdgcn_s_setprio(1);
        PASS(al, bh)
        __builtin_amdgcn_s_setprio(0);
    }
#undef LDS_A
#undef LDS_B
#undef PASS

    // ---- epilogue: score, per-row argmin, cross-wave reduce, atomicMin ----
    __syncthreads();
    u64* red = reinterpret_cast<u64*>(&lds[0][0][0]);   // [256 rows][4 wc] u64 = 8 KB
    float wq[4];
#pragma unroll
    for (int n = 0; n < 4; ++n) wq[n] = wsq[colbase + wc * 64 + n * 16 + frow];

#pragma unroll
    for (int m = 0; m < 8; ++m)
#pragma unroll
        for (int r = 0; r < 4; ++r) {
            u64 b = ~0ull;
#pragma unroll
            for (int n = 0; n < 4; ++n) {
                const int colg = colbase + wc * 64 + n * 16 + frow;
                const float sc = wq[n] - 2.0f * acc[m][n][r];
                const unsigned int fb = __float_as_uint(sc);
                const unsigned int key = (fb & 0x80000000u) ? ~fb : (fb | 0x80000000u);
                const u64 p = ((u64)key << 32) | (unsigned int)colg;
                if (p < b) b = p;
            }
            // reduce over the 16 frow lanes (same kch group)
#pragma unroll
            for (int mk = 1; mk <= 8; mk <<= 1) {
                const u64 o = __shfl_xor(b, mk, 64);
                if (o < b) b = o;
            }
            if (frow == 0) {
                const int rl = wr * 128 + m * 16 + kch * 4 + r;
                red[rl * 4 + wc] = b;
            }
        }
    __syncthreads();
    if (tid < BM) {
        u64 a = red[tid * 4];
#pragma unroll
        for (int j = 1; j < 4; ++j) {
            const u64 o = red[tid * 4 + j];
            if (o < a) a = o;
        }
        atomicMin(part + rowbase + tid, a);
    }
}

// ---------------- kernel 4: decode ----------------
__global__ __launch_bounds__(256) void som_decode(const u64* __restrict__ part,
                                                  int* __restrict__ out) {
    const int row = blockIdx.x * 256 + threadIdx.x;
    if (row >= B_ROWS) return;
    const int idx = (int)(part[row] & 0xFFFFFFFFu);
    out[2 * row] = idx >> 7;      // idx / 128
    out[2 * row + 1] = idx & 127; // idx % 128
}

extern "C" void kernel_launch(void* const* d_in, const int* in_sizes, int n_in,
                              void* d_out, int out_size, void* d_ws, size_t ws_size,
                              hipStream_t stream) {
    const float* xb = (const float*)d_in[0];   // [4096, 256] fp32
    const float* wt = (const float*)d_in[1];   // [16384, 256] fp32
    int* out = (int*)d_out;                    // [4096, 2] int32

    char* ws = (char*)d_ws;
    _Float16* xhi = (_Float16*)(ws);                                   // 2 MB
    _Float16* xlo = (_Float16*)(ws + (size_t)2 * 1024 * 1024);         // 2 MB
    _Float16* whi = (_Float16*)(ws + (size_t)4 * 1024 * 1024);         // 8 MB
    _Float16* wlo = (_Float16*)(ws + (size_t)12 * 1024 * 1024);        // 8 MB
    float*    wsq = (float*)(ws + (size_t)20 * 1024 * 1024);           // 64 KB
    u64*     part = (u64*)(ws + (size_t)20 * 1024 * 1024 + 65536);     // 32 KB

    som_split_w<<<(M_COLS * 32) / 256, 256, 0, stream>>>(wt, whi, wlo, wsq);
    som_split_x<<<(B_ROWS * 32) / 256, 256, 0, stream>>>(xb, xhi, xlo, part);
    som_main<<<(B_ROWS / BM) * (M_COLS / BN), 512, 0, stream>>>(xhi, xlo, whi, wlo, wsq, part);
    som_decode<<<B_ROWS / 256, 256, 0, stream>>>(part, out);
}